// Round 16
// baseline (200.497 us; speedup 1.0000x reference)
//
#include <hip/hip_runtime.h>
#include <hip/hip_bf16.h>

#define PI_F 3.14159265358979323846f
#define C1_EXP 0.18033688f   // log2(e)/8
#define C2_EXP 23.083120f    // 16*log2(e)

typedef __bf16 bf16x8 __attribute__((ext_vector_type(8)));
typedef float f32x4 __attribute__((ext_vector_type(4)));
typedef unsigned int uint32x4 __attribute__((ext_vector_type(4)));

__device__ __forceinline__ bf16x8 neg8(bf16x8 v) {
  union { bf16x8 b; uint32x4 u; } x;
  x.b = v;
  x.u ^= (uint32x4){0x80008000u, 0x80008000u, 0x80008000u, 0x80008000u};
  return x.b;
}

// 3-term split-accumulate: P*Q with P=Ph+Pl, Q=Qh+Ql (drop Pl*Ql ~2^-18)
#define MFMA3(acc, Ph, Pl, Qh, Ql)                                        \
  acc = __builtin_amdgcn_mfma_f32_16x16x32_bf16(Ph, Qh, acc, 0, 0, 0);    \
  acc = __builtin_amdgcn_mfma_f32_16x16x32_bf16(Ph, Ql, acc, 0, 0, 0);    \
  acc = __builtin_amdgcn_mfma_f32_16x16x32_bf16(Pl, Qh, acc, 0, 0, 0);

// Closed-form base-slot -> original column mapping.
__device__ __forceinline__ int slot2n(int slot) {
  const int pi = slot >> 1, im = slot & 1;
  int k1, k2;
  if (pi < 480)      { k1 = 1 + (pi >> 5); k2 = pi & 31; }
  else if (pi < 495) { k1 = 0;  k2 = pi - 479; }
  else if (pi < 510) { k1 = 16; k2 = pi - 494; }
  else if (pi < 514) { k1 = ((pi - 510) >> 1) * 16; k2 = ((pi - 510) & 1) * 16; }
  else               { k1 = 0; k2 = 0; }
  return 2 * (k1 * 32 + k2) + im;
}

// ---------------------------------------------------------------------------
// Kernel 0: twiddle tables, hi/lo split bf16.
// ---------------------------------------------------------------------------
__global__ __launch_bounds__(256) void k_twid(__bf16* __restrict__ tw) {
  for (int e = threadIdx.x; e < 1024; e += 256) {
    const int j = e >> 5, k = e & 31;
    const int t = (j * k) & 31;
    float sv, cv;
    sincosf(2.0f * PI_F * (float)t / 32.0f, &sv, &cv);
    const __bf16 ch = (__bf16)cv;
    const __bf16 sh = (__bf16)sv;
    tw[e] = ch;
    tw[1024 + e] = (__bf16)(cv - (float)ch);
    tw[2048 + e] = sh;
    tw[3072 + e] = (__bf16)(sv - (float)sh);
  }
}

// ---------------------------------------------------------------------------
// Kernel 1: forward FFT2 via split-bf16 MFMA. 2 waves per slice (wave owns
// row-tile mt), 2 slices per block, grid 1024 -> 16 waves/CU.
// RACE FIX (r15 post-mortem): wave mt's transposed-Y write spans ALL LDS rows
// (cols mt-tile), clobbering the partner wave's X staging rows -> a block
// barrier must separate X-fragment register loads from the Y write.
// ---------------------------------------------------------------------------
__global__ __launch_bounds__(256) void k_fft2(const float* __restrict__ x,
                                              float* __restrict__ xr,
                                              float* __restrict__ stats_raw,
                                              const __bf16* __restrict__ tw) {
  __shared__ __align__(16) char smem[30720];
  const int tid = threadIdx.x, lane = tid & 63, wv = tid >> 6;
  const int quad = lane >> 4, q16 = lane & 15;
  for (int i = tid; i < 512; i += 256) {
    const int t = i >> 7, r = (i >> 2) & 31, c8 = (i & 3) * 8;
    *(uint4*)(smem + t * 2560 + r * 80 + c8 * 2) =
        *(const uint4*)(tw + t * 1024 + r * 32 + c8);
  }
  __syncthreads();

  const int slice = blockIdx.x * 2 + (wv >> 1);
  const int mt = wv & 1;
  char* const wr_ = smem + 10240 + (wv >> 1) * 10240;

  // stage this wave's X rows (split); same-wave ds ordering
  const float* xs = x + (size_t)slice * 1024;
#pragma unroll
  for (int u = 0; u < 2; ++u) {
    const int f = (mt * 2 + u) * 64 + lane;
    const float4 v = ((const float4*)xs)[f];
    const int row = f >> 3, c4 = (f & 7) * 4;
    union { unsigned long long q; __bf16 b[4]; } ph, pl;
    ph.b[0] = (__bf16)v.x; ph.b[1] = (__bf16)v.y;
    ph.b[2] = (__bf16)v.z; ph.b[3] = (__bf16)v.w;
    pl.b[0] = (__bf16)(v.x - (float)ph.b[0]);
    pl.b[1] = (__bf16)(v.y - (float)ph.b[1]);
    pl.b[2] = (__bf16)(v.z - (float)ph.b[2]);
    pl.b[3] = (__bf16)(v.w - (float)ph.b[3]);
    *(unsigned long long*)(wr_ + row * 80 + c4 * 2) = ph.q;
    *(unsigned long long*)(wr_ + 2560 + row * 80 + c4 * 2) = pl.q;
  }
  asm volatile("" ::: "memory");

  bf16x8 cch[2], ccl[2], ssh[2], ssl[2];
#pragma unroll
  for (int t2 = 0; t2 < 2; ++t2) {
    const int row = t2 * 16 + q16;
    cch[t2] = *(const bf16x8*)(smem + row * 80 + quad * 16);
    ccl[t2] = *(const bf16x8*)(smem + 2560 + row * 80 + quad * 16);
    ssh[t2] = *(const bf16x8*)(smem + 5120 + row * 80 + quad * 16);
    ssl[t2] = *(const bf16x8*)(smem + 7680 + row * 80 + quad * 16);
  }
  bf16x8 xh, xl;
  {
    const int row = mt * 16 + q16;
    xh = *(const bf16x8*)(wr_ + row * 80 + quad * 16);
    xl = *(const bf16x8*)(wr_ + 2560 + row * 80 + quad * 16);
  }

  // pass 1 (this wave's mt): Yre = X@Cc, Yim = -(X@Ss)
  f32x4 yre[2] = {}, yim[2] = {};
#pragma unroll
  for (int nt = 0; nt < 2; ++nt) {
    MFMA3(yre[nt], xh, xl, cch[nt], ccl[nt]);
    MFMA3(yim[nt], xh, xl, ssh[nt], ssl[nt]);
  }

  __syncthreads();  // RACE FIX: partner wave must finish its X-frag loads
                    // before our transposed-Y write clobbers its rows

  // write Yt transposed + split (this wave's mt columns)
#pragma unroll
  for (int nt = 0; nt < 2; ++nt) {
    char* base = wr_ + (nt * 16 + q16) * 80 + (mt * 16 + quad * 4) * 2;
    union { unsigned long long q; __bf16 b[4]; } h, l;
#pragma unroll
    for (int r = 0; r < 4; ++r) {
      const float v = yre[nt][r];
      h.b[r] = (__bf16)v; l.b[r] = (__bf16)(v - (float)h.b[r]);
    }
    *(unsigned long long*)(base) = h.q;
    *(unsigned long long*)(base + 2560) = l.q;
#pragma unroll
    for (int r = 0; r < 4; ++r) {
      const float v = -yim[nt][r];
      h.b[r] = (__bf16)v; l.b[r] = (__bf16)(v - (float)h.b[r]);
    }
    *(unsigned long long*)(base + 5120) = h.q;
    *(unsigned long long*)(base + 7680) = l.q;
  }
  __syncthreads();  // cross-wave: both waves' Y columns must land

  bf16x8 yreh[2], yrel[2], yimh[2], yiml[2];
#pragma unroll
  for (int nt = 0; nt < 2; ++nt) {
    const int row = nt * 16 + q16;
    yreh[nt] = *(const bf16x8*)(wr_ + row * 80 + quad * 16);
    yrel[nt] = *(const bf16x8*)(wr_ + 2560 + row * 80 + quad * 16);
    yimh[nt] = *(const bf16x8*)(wr_ + 5120 + row * 80 + quad * 16);
    yiml[nt] = *(const bf16x8*)(wr_ + 7680 + row * 80 + quad * 16);
  }

  // pass 2 (rows mt): Zre = Cc@Yre + Ss@Yim ; Zim = Cc@Yim - Ss@Yre
  const bf16x8 ssnh = neg8(ssh[mt]), ssnl = neg8(ssl[mt]);
  f32x4 zre[2] = {}, zim[2] = {};
#pragma unroll
  for (int nt = 0; nt < 2; ++nt) {
    MFMA3(zre[nt], cch[mt], ccl[mt], yreh[nt], yrel[nt]);
    MFMA3(zre[nt], ssh[mt], ssl[mt], yimh[nt], yiml[nt]);
    MFMA3(zim[nt], cch[mt], ccl[mt], yimh[nt], yiml[nt]);
    MFMA3(zim[nt], ssnh, ssnl, yreh[nt], yrel[nt]);
  }

  // stats + store
  float* op = xr + (size_t)slice * 2048;
  float s1 = 0.f, s2 = 0.f;
#pragma unroll
  for (int nt = 0; nt < 2; ++nt)
#pragma unroll
    for (int r = 0; r < 4; ++r) {
      const int k1 = mt * 16 + quad * 4 + r;
      const int k2 = nt * 16 + q16;
      const float a = zre[nt][r], bimg = zim[nt][r];
      s1 += a + bimg;
      s2 += a * a + bimg * bimg;
      float2 st; st.x = a; st.y = bimg;
      *(float2*)(op + 2 * (k1 * 32 + k2)) = st;
    }
#pragma unroll
  for (int off = 1; off <= 32; off <<= 1) {
    s1 += __shfl_xor(s1, off);
    s2 += __shfl_xor(s2, off);
  }
  if (lane == 0) {
    const int bg = (slice >> 8) * 32 + ((slice & 255) >> 3);
    atomicAdd(&stats_raw[bg * 2], s1);
    atomicAdd(&stats_raw[bg * 2 + 1], s2);
  }
}

// ---------------------------------------------------------------------------
// Kernel 2: mirror-correction vectors (coalesced); unchanged.
// ---------------------------------------------------------------------------
__global__ __launch_bounds__(256) void k_uvec(const float* __restrict__ stats_raw,
                                              const float* __restrict__ gn_w,
                                              const float* __restrict__ gn_b,
                                              const float* __restrict__ qkv_w,
                                              const float* __restrict__ qkv_b,
                                              float* __restrict__ uk,
                                              float* __restrict__ uv) {
  const int blk = blockIdx.x;
  const int tid = threadIdx.x;
  const int b = blk >> 3, h = (blk >> 1) & 3, role = blk & 1;
  __shared__ float Bsh[256];
  {
    const int g = tid >> 3;
    const float S = stats_raw[(b * 32 + g) * 2];
    const float S2 = stats_raw[(b * 32 + g) * 2 + 1];
    const float mean = S * (1.0f / 16384.0f);
    const float var = S2 * (1.0f / 16384.0f) - mean * mean;
    const float rstd = rsqrtf(var + 1e-5f);
    Bsh[tid] = gn_b[tid] - mean * rstd * gn_w[tid];
  }
  __syncthreads();
  const int cp = tid >> 2, seg = tid & 3;
  const int row = h * 192 + 64 + role * 64 + cp;
  const float* wr_ = qkv_w + (size_t)row * 256 + seg * 64;
  const float* bs = Bsh + seg * 64;
  float s = 0.f;
#pragma unroll
  for (int i = 0; i < 16; ++i) {
    const float4 w4 = *(const float4*)(wr_ + i * 4);
    const float4 b4 = *(const float4*)(bs + i * 4);
    s += w4.x * b4.x + w4.y * b4.y + w4.z * b4.z + w4.w * b4.w;
  }
  s += __shfl_xor(s, 1);
  s += __shfl_xor(s, 2);
  if (seg == 0) {
    float* dst = (role == 0) ? uk : uv;
    dst[(size_t)(b * 4 + h) * 64 + cp] = s + qkv_b[row];
  }
}

// ---------------------------------------------------------------------------
// Kernel 3: GroupNorm apply + transpose to bf16 X^T [b][n][c]; unchanged.
// ---------------------------------------------------------------------------
__global__ __launch_bounds__(256) void k_gntrans(const float* __restrict__ xr,
                                                 const float* __restrict__ stats_raw,
                                                 const float* __restrict__ w,
                                                 const float* __restrict__ bias,
                                                 __bf16* __restrict__ xt) {
  const int n0 = blockIdx.x * 64;
  const int c0 = blockIdx.y * 64;
  const int b = blockIdx.z;
  __shared__ __bf16 Lt[64][72];
  const int tid = threadIdx.x;
  for (int i = tid; i < 1024; i += 256) {
    const int cl = i >> 4, c = c0 + cl, nl = (i & 15) * 4;
    const float S = stats_raw[(b * 32 + (c >> 3)) * 2];
    const float S2 = stats_raw[(b * 32 + (c >> 3)) * 2 + 1];
    const float mean = S * (1.0f / 16384.0f);
    const float var = S2 * (1.0f / 16384.0f) - mean * mean;
    const float rstd = rsqrtf(var + 1e-5f);
    const float sc = rstd * w[c];
    const float sh = bias[c] - mean * sc;
    const float4 v = *(const float4*)(xr + ((size_t)b * 256 + c) * 2048 + n0 + nl);
    Lt[nl][cl] = (__bf16)(v.x * sc + sh);
    Lt[nl + 1][cl] = (__bf16)(v.y * sc + sh);
    Lt[nl + 2][cl] = (__bf16)(v.z * sc + sh);
    Lt[nl + 3][cl] = (__bf16)(v.w * sc + sh);
  }
  __syncthreads();
  __bf16* dst = xt + (size_t)b * 524288 + (size_t)n0 * 256 + c0;
  for (int i = tid; i < 512; i += 256) {
    const int nl = i >> 3, cch = (i & 7) * 8;
    *(uint4*)(dst + (size_t)nl * 256 + cch) = *(const uint4*)&Lt[nl][cch];
  }
}

// ---------------------------------------------------------------------------
// Kernel 4: QKV GEMM (bf16 MFMA), double-buffered LDS; unchanged.
// ---------------------------------------------------------------------------
__global__ __launch_bounds__(256) void k_gemm_qkv(const float* __restrict__ W,
                                                  const __bf16* __restrict__ X,
                                                  const float* __restrict__ bias,
                                                  const float* __restrict__ uk,
                                                  float* __restrict__ dq,
                                                  __bf16* __restrict__ Qt,
                                                  __bf16* __restrict__ Kt,
                                                  __bf16* __restrict__ Vt) {
  const int tx = blockIdx.x;
  const int b = blockIdx.y;
  int role, hd, nt;
  if (tx < 64) { role = 0; hd = tx >> 4; nt = tx & 15; }
  else if (tx < 100) { role = 1; const int i = tx - 64; hd = i / 9; nt = i - hd * 9; }
  else { role = 2; const int i = tx - 100; hd = i / 9; nt = i - hd * 9; }
  const int n0 = nt * 128;
  const int bo = hd * 192 + role * 64;
  const __bf16* Xb = X + (size_t)b * 524288;

  __shared__ __align__(16) char smem[30720];
  __bf16 (*Ot)[72] = (__bf16(*)[72])smem;
  __bf16 (*Ot2)[136] = (__bf16(*)[136])smem;

  const int tid = threadIdx.x, lane = tid & 63, wv = tid >> 6;
  const int quad = lane >> 4, q16 = lane & 15, wn = wv * 32;

  const int rowA = tid >> 2, chA = (tid & 3) * 8;
  const int browB0 = tid >> 2, bchB = (tid & 3) * 8;
  const float* wA = W + (size_t)(bo + rowA) * 256 + chA;

  const int s0r = n0 + browB0, s1r = n0 + browB0 + 64;
  const int pn0 = (role == 0) ? s0r : slot2n(s0r);
  const int pn1 = (role == 0) ? s1r : slot2n(s1r);

  float4 aP0 = *(const float4*)(wA);
  float4 aP1 = *(const float4*)(wA + 4);
  uint4 bP0 = *(const uint4*)(Xb + (size_t)pn0 * 256 + bchB);
  uint4 bP1 = *(const uint4*)(Xb + (size_t)pn1 * 256 + bchB);

  f32x4 acc[4][2] = {};
  int bsel = 0;
  for (int k0 = 0; k0 < 256; k0 += 32) {
    char* const Ab = smem + bsel;
    char* const Bb = smem + bsel + 5120;
    {
      union { uint4 u; __bf16 h[8]; } pa;
      pa.h[0] = (__bf16)aP0.x; pa.h[1] = (__bf16)aP0.y;
      pa.h[2] = (__bf16)aP0.z; pa.h[3] = (__bf16)aP0.w;
      pa.h[4] = (__bf16)aP1.x; pa.h[5] = (__bf16)aP1.y;
      pa.h[6] = (__bf16)aP1.z; pa.h[7] = (__bf16)aP1.w;
      *(uint4*)(Ab + rowA * 80 + chA * 2) = pa.u;
      *(uint4*)(Bb + browB0 * 80 + bchB * 2) = bP0;
      *(uint4*)(Bb + (browB0 + 64) * 80 + bchB * 2) = bP1;
    }
    __syncthreads();
    if (k0 + 32 < 256) {
      const int kn = k0 + 32;
      aP0 = *(const float4*)(wA + kn);
      aP1 = *(const float4*)(wA + kn + 4);
      bP0 = *(const uint4*)(Xb + (size_t)pn0 * 256 + kn + bchB);
      bP1 = *(const uint4*)(Xb + (size_t)pn1 * 256 + kn + bchB);
    }
    bf16x8 af[4], bfr[2];
#pragma unroll
    for (int mt = 0; mt < 4; ++mt)
      af[mt] = *(const bf16x8*)(Ab + (mt * 16 + q16) * 80 + quad * 16);
#pragma unroll
    for (int jn = 0; jn < 2; ++jn)
      bfr[jn] = *(const bf16x8*)(Bb + (wn + jn * 16 + q16) * 80 + quad * 16);
#pragma unroll
    for (int mt = 0; mt < 4; ++mt)
#pragma unroll
      for (int jn = 0; jn < 2; ++jn)
        acc[mt][jn] = __builtin_amdgcn_mfma_f32_16x16x32_bf16(af[mt], bfr[jn], acc[mt][jn], 0, 0, 0);
    bsel ^= 15360;
  }
  __syncthreads();

  const int bh = b * 4 + hd;
  if (role == 2) {
#pragma unroll
    for (int mt = 0; mt < 4; ++mt)
#pragma unroll
      for (int r = 0; r < 4; ++r) {
        const int c = mt * 16 + quad * 4 + r;
        const float bv = bias[bo + c];
#pragma unroll
        for (int jn = 0; jn < 2; ++jn)
          Ot2[c][wn + jn * 16 + q16] = (__bf16)(acc[mt][jn][r] + bv);
      }
    __syncthreads();
    __bf16* dst = Vt + (size_t)bh * 73728;  // [c][1152]
    for (int i = tid; i < 1024; i += 256) {
      const int c = i >> 4, sg = (i & 15) * 8;
      *(uint4*)(dst + (size_t)c * 1152 + n0 + sg) = *(const uint4*)&Ot2[c][sg];
    }
  } else {
    __bf16* dst = (role == 0 ? Qt + (size_t)bh * 131072
                             : Kt + (size_t)bh * 73728);  // [n][64]
#pragma unroll
    for (int mt = 0; mt < 4; ++mt)
#pragma unroll
      for (int r = 0; r < 4; ++r) {
        const int c = mt * 16 + quad * 4 + r;
        const float bv = bias[bo + c];
#pragma unroll
        for (int jn = 0; jn < 2; ++jn)
          Ot[wn + jn * 16 + q16][c] = (__bf16)(acc[mt][jn][r] + bv);
      }
    __syncthreads();
    for (int i = tid; i < 1024; i += 256) {
      const int nl = i >> 3, cch = (i & 7) * 8;
      *(uint4*)(dst + (size_t)(n0 + nl) * 64 + cch) = *(const uint4*)&Ot[nl][cch];
    }
    if (role == 0 && tid < 128) {
      const float* ukp = uk + (size_t)bh * 64;
      float dv = 0.f;
#pragma unroll
      for (int g8 = 0; g8 < 8; ++g8) {
        const bf16x8 qv = *(const bf16x8*)&Ot[tid][g8 * 8];
#pragma unroll
        for (int k = 0; k < 8; ++k) dv += (float)qv[k] * ukp[g8 * 8 + k];
      }
      dq[(size_t)bh * 2048 + n0 + tid] = dv * (2.0f * C1_EXP);
    }
  }
}

// ---------------------------------------------------------------------------
// Kernel 5: MFMA flash attention; unchanged (weight-folded exp biases).
// ---------------------------------------------------------------------------
__global__ __launch_bounds__(256) void k_attn_mfma(const __bf16* __restrict__ Qt,
                                                   const __bf16* __restrict__ Kt,
                                                   const __bf16* __restrict__ Vt,
                                                   const float* __restrict__ dq,
                                                   const float* __restrict__ uv,
                                                   __bf16* __restrict__ opart,
                                                   float* __restrict__ lpart) {
  const int t0 = blockIdx.x * 128;
  const int part = blockIdx.y;  // 0..2
  const int bh = blockIdx.z;
  const __bf16* kt = Kt + (size_t)bh * 73728;
  const __bf16* vt = Vt + (size_t)bh * 73728;

  __shared__ __align__(16) char smem[16384];

  const int tid = threadIdx.x, lane = tid & 63, wv = tid >> 6;
  const int quad = lane >> 4, q16 = lane & 15;
  const int wband = wv * 32;

  const int rK = tid >> 3, gK = tid & 7;
  char* const kw = smem + rK * 128 + ((gK ^ (rK & 7)) * 16);
  const int cV = tid >> 2, gV = tid & 3;
  char* const vw = smem + 4096 + (cV >> 1) * 128 +
                   ((((cV & 1) * 4 + gV) ^ ((cV >> 1) & 7)) * 16);
  const __bf16* const kg = kt + (size_t)rK * 64 + gK * 8;
  const __bf16* const vg = vt + (size_t)cV * 1152 + gV * 8;

  const char* krp[2][2];
#pragma unroll
  for (int j = 0; j < 2; ++j)
#pragma unroll
    for (int kk = 0; kk < 2; ++kk)
      krp[j][kk] = smem + (j * 16 + q16) * 128 + (((kk * 4 + quad) ^ (q16 & 7)) * 16);
  const int a7 = (q16 >> 1) & 7, p1 = q16 & 1;
  const char* vrp[4];
#pragma unroll
  for (int jc = 0; jc < 4; ++jc)
    vrp[jc] = smem + 4096 + (jc * 8 + (q16 >> 1)) * 128 +
              (((p1 * 4 + quad) ^ a7) * 16);
  char* pwp[2][2];
  const char* prp[2];
#pragma unroll
  for (int b = 0; b < 2; ++b) {
    const int mrow = ((wband + b * 16) >> 1) + (q16 >> 1);
    prp[b] = smem + 8192 + mrow * 128 + (((p1 * 4 + quad) ^ a7) * 16);
#pragma unroll
    for (int j = 0; j < 2; ++j)
      pwp[b][j] = smem + 8192 + mrow * 128 +
                  (((p1 * 4 + j * 2 + (quad >> 1)) ^ a7) * 16) + (quad & 1) * 8;
  }

  const __bf16* qbase = Qt + (size_t)bh * 131072;
  bf16x8 bq[2][2];
  float Dm[2];
  float4 uv4[4];
#pragma unroll
  for (int b = 0; b < 2; ++b) {
    const int t = t0 + wband + b * 16 + q16;
    const __bf16* qp = qbase + (size_t)t * 64 + quad * 8;
    bq[b][0] = *(const bf16x8*)qp;
    bq[b][1] = *(const bf16x8*)(qp + 32);
    Dm[b] = dq[(size_t)bh * 2048 + t] - C2_EXP;
  }
  {
    const float* uvp = uv + (size_t)bh * 64;
#pragma unroll
    for (int jc = 0; jc < 4; ++jc)
      uv4[jc] = *(const float4*)(uvp + jc * 16 + quad * 4);
  }

  f32x4 oacc[2][4] = {};
  float lsum[2] = {0.f, 0.f};
  float spsum[2] = {0.f, 0.f};

  const int sbase = part * 352, send = sbase + 352;
  uint4 kA = *(const uint4*)(kg + (size_t)sbase * 64);
  uint4 vA = *(const uint4*)(vg + sbase);

  for (int s0 = sbase; s0 < send; s0 += 32) {
    *(uint4*)kw = kA;
    *(uint4*)vw = vA;
    __syncthreads();
    if (s0 + 32 < send) {
      kA = *(const uint4*)(kg + (size_t)(s0 + 32) * 64);
      vA = *(const uint4*)(vg + s0 + 32);
    }

    f32x4 sacc[2][2] = {};
#pragma unroll
    for (int j = 0; j < 2; ++j)
#pragma unroll
      for (int kk = 0; kk < 2; ++kk) {
        const bf16x8 ak = *(const bf16x8*)krp[j][kk];
        sacc[0][j] = __builtin_amdgcn_mfma_f32_16x16x32_bf16(ak, bq[0][kk], sacc[0][j], 0, 0, 0);
        sacc[1][j] = __builtin_amdgcn_mfma_f32_16x16x32_bf16(ak, bq[1][kk], sacc[1][j], 0, 0, 0);
      }

#pragma unroll
    for (int b = 0; b < 2; ++b) {
      float lacc = 0.f, spacc = 0.f;
#pragma unroll
      for (int j = 0; j < 2; ++j) {
        const int sg = s0 + j * 16 + quad * 4;
        const float B0 = (sg < 1020) ? (1.0f - C2_EXP)
                                     : ((sg < 1028) ? -C2_EXP : -1e30f);
        const float B2 = (sg + 2 < 1020) ? (1.0f - C2_EXP)
                                         : ((sg + 2 < 1028) ? -C2_EXP : -1e30f);
        const float Bv1 = (sg + 1 < 1028) ? -C2_EXP : -1e30f;
        const float Bv3 = (sg + 3 < 1028) ? -C2_EXP : -1e30f;
        const float Bm1 = (sg + 1 < 1020) ? Dm[b] : -1e30f;
        const float Bm3 = (sg + 3 < 1020) ? Dm[b] : -1e30f;
        const float P0  = exp2f(fmaf(sacc[b][j][0], C1_EXP, B0));
        const float Pv1 = exp2f(fmaf(sacc[b][j][1], C1_EXP, Bv1));
        const float P2  = exp2f(fmaf(sacc[b][j][2], C1_EXP, B2));
        const float Pv3 = exp2f(fmaf(sacc[b][j][3], C1_EXP, Bv3));
        const float pm1 = exp2f(fmaf(sacc[b][j][1], -C1_EXP, Bm1));
        const float pm3 = exp2f(fmaf(sacc[b][j][3], -C1_EXP, Bm3));
        lacc += (P0 + P2) + (Pv1 + Pv3) + (pm1 + pm3);
        spacc += pm1 + pm3;
        union { uint2 u; __bf16 h[4]; } pk;
        pk.h[0] = (__bf16)P0;
        pk.h[1] = (__bf16)(Pv1 - pm1);
        pk.h[2] = (__bf16)P2;
        pk.h[3] = (__bf16)(Pv3 - pm3);
        *(uint2*)pwp[b][j] = pk.u;
      }
      lsum[b] += lacc;
      spsum[b] += spacc;
    }
    asm volatile("" ::: "memory");

    bf16x8 bp[2];
    bp[0] = *(const bf16x8*)prp[0];
    bp[1] = *(const bf16x8*)prp[1];
#pragma unroll
    for (int jc = 0; jc < 4; ++jc) {
      const bf16x8 av = *(const bf16x8*)vrp[jc];
      oacc[0][jc] = __builtin_amdgcn_mfma_f32_16x16x32_bf16(av, bp[0], oacc[0][jc], 0, 0, 0);
      oacc[1][jc] = __builtin_amdgcn_mfma_f32_16x16x32_bf16(av, bp[1], oacc[1][jc], 0, 0, 0);
    }
    __syncthreads();
  }

#pragma unroll
  for (int b = 0; b < 2; ++b) {
    float l = lsum[b], sp = spsum[b];
    l += __shfl_xor(l, 16);
    l += __shfl_xor(l, 32);
    sp += __shfl_xor(sp, 16);
    sp += __shfl_xor(sp, 32);
    const float sp2 = 2.0f * sp;
    const int t = t0 + wband + b * 16 + q16;
    const size_t row = (size_t)(bh * 3 + part) * 2048 + t;
    if (quad == 0) lpart[row] = l;
    __bf16* opp = opart + row * 64;
#pragma unroll
    for (int jc = 0; jc < 4; ++jc) {
      union { uint2 u; __bf16 h[4]; } pk;
      pk.h[0] = (__bf16)(oacc[b][jc][0] + sp2 * uv4[jc].x);
      pk.h[1] = (__bf16)(oacc[b][jc][1] + sp2 * uv4[jc].y);
      pk.h[2] = (__bf16)(oacc[b][jc][2] + sp2 * uv4[jc].z);
      pk.h[3] = (__bf16)(oacc[b][jc][3] + sp2 * uv4[jc].w);
      *(uint2*)(opp + jc * 16 + quad * 4) = pk.u;
    }
  }
}

// ---------------------------------------------------------------------------
// Kernel 6: proj GEMM (bf16 MFMA), double-buffered, fused 3-way combine;
// unchanged.
// ---------------------------------------------------------------------------
__global__ __launch_bounds__(256) void k_gemm_proj(const float* __restrict__ W,
                                                   const __bf16* __restrict__ opart,
                                                   const float* __restrict__ lpart,
                                                   const float* __restrict__ bias,
                                                   float* __restrict__ C) {
  const int n0 = blockIdx.x * 128;
  const int bo = blockIdx.y * 64;
  const int b = blockIdx.z;
  float* Cb = C + (size_t)b * 524288;

  __shared__ __align__(16) char smem[30720];

  const int tid = threadIdx.x, lane = tid & 63, wv = tid >> 6;
  const int quad = lane >> 4, q16 = lane & 15, wn = wv * 32;

  const int rowA = tid >> 2, chA = (tid & 3) * 8;
  const int browB0 = tid >> 2, bchB = (tid & 3) * 8;
  const float* wA = W + (size_t)(bo + rowA) * 256 + chA;

  float linv[2][4];
#pragma unroll
  for (int g = 0; g < 2; ++g) {
    const int t = n0 + browB0 + g * 64;
#pragma unroll
    for (int hd = 0; hd < 4; ++hd) {
      const size_t rr = (size_t)((b * 4 + hd) * 3) * 2048 + t;
      linv[g][hd] = 1.0f / (lpart[rr] + lpart[rr + 2048] + lpart[rr + 4096]);
    }
  }

  float4 aP0 = *(const float4*)(wA);
  float4 aP1 = *(const float4*)(wA + 4);
  bf16x8 oP[2][3];
#pragma unroll
  for (int g = 0; g < 2; ++g) {
    const int t = n0 + browB0 + g * 64;
    const size_t rr = (size_t)(b * 4 * 3) * 2048 + t;
#pragma unroll
    for (int p = 0; p < 3; ++p)
      oP[g][p] = *(const bf16x8*)(opart + (rr + p * 2048) * 64 + bchB);
  }

  f32x4 acc[4][2] = {};
  int bsel = 0;
  for (int k0 = 0; k0 < 256; k0 += 32) {
    char* const Ab = smem + bsel;
    char* const Bb = smem + bsel + 5120;
    {
      union { uint4 u; __bf16 h[8]; } pa;
      pa.h[0] = (__bf16)aP0.x; pa.h[1] = (__bf16)aP0.y;
      pa.h[2] = (__bf16)aP0.z; pa.h[3] = (__bf16)aP0.w;
      pa.h[4] = (__bf16)aP1.x; pa.h[5] = (__bf16)aP1.y;
      pa.h[6] = (__bf16)aP1.z; pa.h[7] = (__bf16)aP1.w;
      *(uint4*)(Ab + rowA * 80 + chA * 2) = pa.u;
      const int hd = (k0 + bchB) >> 6;
#pragma unroll
      for (int g = 0; g < 2; ++g) {
        const float inv = linv[g][hd];
        bf16x8 res;
#pragma unroll
        for (int k = 0; k < 8; ++k)
          res[k] = (__bf16)((((float)oP[g][0][k] + (float)oP[g][1][k]) +
                             (float)oP[g][2][k]) * inv);
        *(bf16x8*)(Bb + (browB0 + g * 64) * 80 + bchB * 2) = res;
      }
    }
    __syncthreads();
    if (k0 + 32 < 256) {
      const int kn = k0 + 32;
      aP0 = *(const float4*)(wA + kn);
      aP1 = *(const float4*)(wA + kn + 4);
      const int c = kn + bchB;
      const int hd = c >> 6, cu = c & 63;
#pragma unroll
      for (int g = 0; g < 2; ++g) {
        const int t = n0 + browB0 + g * 64;
        const size_t rr = (size_t)((b * 4 + hd) * 3) * 2048 + t;
#pragma unroll
        for (int p = 0; p < 3; ++p)
          oP[g][p] = *(const bf16x8*)(opart + (rr + p * 2048) * 64 + cu);
      }
    }
    bf16x8 af[4], bfr[2];
#pragma unroll
    for (int mt = 0; mt < 4; ++mt)
      af[mt] = *(const bf16x8*)(Ab + (mt * 16 + q16) * 80 + quad * 16);
#pragma unroll
    for (int jn = 0; jn < 2; ++jn)
      bfr[jn] = *(const bf16x8*)(Bb + (wn + jn * 16 + q16) * 80 + quad * 16);
#pragma unroll
    for (int mt = 0; mt < 4; ++mt)
#pragma unroll
      for (int jn = 0; jn < 2; ++jn)
        acc[mt][jn] = __builtin_amdgcn_mfma_f32_16x16x32_bf16(af[mt], bfr[jn], acc[mt][jn], 0, 0, 0);
    bsel ^= 15360;
  }

#pragma unroll
  for (int mt = 0; mt < 4; ++mt)
#pragma unroll
    for (int r = 0; r < 4; ++r) {
      const int o = bo + mt * 16 + quad * 4 + r;
      const float bv = bias[o];
#pragma unroll
      for (int jn = 0; jn < 2; ++jn)
        Cb[(size_t)o * 2048 + n0 + wn + jn * 16 + q16] = acc[mt][jn][r] + bv;
    }
}

// ---------------------------------------------------------------------------
// Kernel 7: inverse FFT2 via split-bf16 MFMA. 2 waves per slice; same race
// fix as k_fft2 (barrier before the transposed-Y write).
// ---------------------------------------------------------------------------
__global__ __launch_bounds__(256) void k_ifft2(const float* __restrict__ spec,
                                               float* __restrict__ out,
                                               const __bf16* __restrict__ tw) {
  __shared__ __align__(16) char smem[30720];
  const int tid = threadIdx.x, lane = tid & 63, wv = tid >> 6;
  const int quad = lane >> 4, q16 = lane & 15;
  for (int i = tid; i < 512; i += 256) {
    const int t = i >> 7, r = (i >> 2) & 31, c8 = (i & 3) * 8;
    *(uint4*)(smem + t * 2560 + r * 80 + c8 * 2) =
        *(const uint4*)(tw + t * 1024 + r * 32 + c8);
  }
  __syncthreads();

  const int slice = blockIdx.x * 2 + (wv >> 1);
  const int mt = wv & 1;
  char* const wr_ = smem + 10240 + (wv >> 1) * 10240;

  const float* sp = spec + (size_t)slice * 2048;
#pragma unroll
  for (int u = 0; u < 4; ++u) {
    const int f = (mt * 4 + u) * 64 + lane;  // k1 in this wave's rows
    const float4 v = ((const float4*)sp)[f];
    const int k1 = f >> 4, k2 = (f & 15) * 2;
    char* base = wr_ + k1 * 80 + k2 * 2;
    union { unsigned int w; __bf16 b[2]; } p;
    const __bf16 rh0 = (__bf16)v.x, rh1 = (__bf16)v.z;
    const __bf16 ih0 = (__bf16)v.y, ih1 = (__bf16)v.w;
    p.b[0] = rh0; p.b[1] = rh1; *(unsigned int*)(base) = p.w;
    p.b[0] = (__bf16)(v.x - (float)rh0);
    p.b[1] = (__bf16)(v.z - (float)rh1); *(unsigned int*)(base + 2560) = p.w;
    p.b[0] = ih0; p.b[1] = ih1; *(unsigned int*)(base + 5120) = p.w;
    p.b[0] = (__bf16)(v.y - (float)ih0);
    p.b[1] = (__bf16)(v.w - (float)ih1); *(unsigned int*)(base + 7680) = p.w;
  }
  asm volatile("" ::: "memory");

  bf16x8 cch[2], ccl[2], ssh[2], ssl[2];
#pragma unroll
  for (int t2 = 0; t2 < 2; ++t2) {
    const int row = t2 * 16 + q16;
    cch[t2] = *(const bf16x8*)(smem + row * 80 + quad * 16);
    ccl[t2] = *(const bf16x8*)(smem + 2560 + row * 80 + quad * 16);
    ssh[t2] = *(const bf16x8*)(smem + 5120 + row * 80 + quad * 16);
    ssl[t2] = *(const bf16x8*)(smem + 7680 + row * 80 + quad * 16);
  }
  bf16x8 xreh, xrel, ximh, ximl;
  {
    const int row = mt * 16 + q16;
    xreh = *(const bf16x8*)(wr_ + row * 80 + quad * 16);
    xrel = *(const bf16x8*)(wr_ + 2560 + row * 80 + quad * 16);
    ximh = *(const bf16x8*)(wr_ + 5120 + row * 80 + quad * 16);
    ximl = *(const bf16x8*)(wr_ + 7680 + row * 80 + quad * 16);
  }
  bf16x8 ssnhB[2], ssnlB[2];
  ssnhB[0] = neg8(ssh[0]); ssnhB[1] = neg8(ssh[1]);
  ssnlB[0] = neg8(ssl[0]); ssnlB[1] = neg8(ssl[1]);

  // pass 1 (this wave's mt): Yre = Xre@Cc - Xim@Ss ; Yim = Xre@Ss + Xim@Cc
  f32x4 yre[2] = {}, yim[2] = {};
#pragma unroll
  for (int nt = 0; nt < 2; ++nt) {
    MFMA3(yre[nt], xreh, xrel, cch[nt], ccl[nt]);
    MFMA3(yre[nt], ximh, ximl, ssnhB[nt], ssnlB[nt]);
    MFMA3(yim[nt], xreh, xrel, ssh[nt], ssl[nt]);
    MFMA3(yim[nt], ximh, ximl, cch[nt], ccl[nt]);
  }

  __syncthreads();  // RACE FIX: partner wave's X-frag loads must complete
                    // before our transposed-Y write clobbers its rows

  // write Yt transposed + split
#pragma unroll
  for (int nt = 0; nt < 2; ++nt) {
    char* base = wr_ + (nt * 16 + q16) * 80 + (mt * 16 + quad * 4) * 2;
    union { unsigned long long q; __bf16 b[4]; } h, l;
#pragma unroll
    for (int r = 0; r < 4; ++r) {
      const float v = yre[nt][r];
      h.b[r] = (__bf16)v; l.b[r] = (__bf16)(v - (float)h.b[r]);
    }
    *(unsigned long long*)(base) = h.q;
    *(unsigned long long*)(base + 2560) = l.q;
#pragma unroll
    for (int r = 0; r < 4; ++r) {
      const float v = yim[nt][r];
      h.b[r] = (__bf16)v; l.b[r] = (__bf16)(v - (float)h.b[r]);
    }
    *(unsigned long long*)(base + 5120) = h.q;
    *(unsigned long long*)(base + 7680) = l.q;
  }
  __syncthreads();  // cross-wave

  bf16x8 yreh[2], yrel[2], yimh[2], yiml[2];
#pragma unroll
  for (int nt = 0; nt < 2; ++nt) {
    const int row = nt * 16 + q16;
    yreh[nt] = *(const bf16x8*)(wr_ + row * 80 + quad * 16);
    yrel[nt] = *(const bf16x8*)(wr_ + 2560 + row * 80 + quad * 16);
    yimh[nt] = *(const bf16x8*)(wr_ + 5120 + row * 80 + quad * 16);
    yiml[nt] = *(const bf16x8*)(wr_ + 7680 + row * 80 + quad * 16);
  }

  // pass 2 (rows mt): Zre = Cc@Yre - Ss@Yim ; Zim = Cc@Yim + Ss@Yre
  f32x4 zre[2] = {}, zim[2] = {};
#pragma unroll
  for (int nt = 0; nt < 2; ++nt) {
    MFMA3(zre[nt], cch[mt], ccl[mt], yreh[nt], yrel[nt]);
    MFMA3(zre[nt], ssnhB[mt], ssnlB[mt], yimh[nt], yiml[nt]);
    MFMA3(zim[nt], cch[mt], ccl[mt], yimh[nt], yiml[nt]);
    MFMA3(zim[nt], ssh[mt], ssl[mt], yreh[nt], yrel[nt]);
  }

  float* op = out + (size_t)slice * 2048;
#pragma unroll
  for (int nt = 0; nt < 2; ++nt)
#pragma unroll
    for (int r = 0; r < 4; ++r) {
      const int n1 = mt * 16 + quad * 4 + r;
      const int n2 = nt * 16 + q16;
      float2 st;
      st.x = zre[nt][r] * (1.0f / 1024.0f);
      st.y = zim[nt][r] * (1.0f / 1024.0f);
      *(float2*)(op + 2 * (n1 * 32 + n2)) = st;
    }
}

// ---------------------------------------------------------------------------
extern "C" void kernel_launch(void* const* d_in, const int* in_sizes, int n_in,
                              void* d_out, int out_size, void* d_ws, size_t ws_size,
                              hipStream_t stream) {
  (void)in_sizes; (void)n_in; (void)out_size; (void)ws_size;
  const float* x      = (const float*)d_in[0];
  const float* gn_w   = (const float*)d_in[1];
  const float* gn_b   = (const float*)d_in[2];
  const float* qkv_w  = (const float*)d_in[3];
  const float* qkv_b  = (const float*)d_in[4];
  const float* proj_w = (const float*)d_in[5];
  const float* proj_b = (const float*)d_in[6];
  float* out = (float*)d_out;

  float* spec  = (float*)d_ws;
  __bf16* Qt   = (__bf16*)(spec + 4194304);   // 4194304 elems
  __bf16* Kt   = Qt + 4194304;                // 2359296 elems (32*1152*64)
  __bf16* Vt   = Kt + 2359296;                // 2359296 elems
  float* stats = (float*)(Vt + 2359296);      // 512
  float* xr    = stats + 512;                 // 4194304 floats
  __bf16* xt   = (__bf16*)(xr + 4194304);     // 4194304 bf16
  __bf16* opart = (__bf16*)xr;                // 12582912 bf16 (clobbers xr+xt)
  float*  lpart = (float*)(opart + 12582912); // 196608
  float*  dq    = lpart + 196608;             // 65536
  float*  uk    = dq + 65536;                 // 2048
  float*  uv    = uk + 2048;                  // 2048
  __bf16* tw    = (__bf16*)(uv + 2048);       // 4096 bf16 twiddle tables

  hipMemsetAsync(stats, 0, 512 * sizeof(float), stream);
  k_twid<<<1, 256, 0, stream>>>(tw);
  k_fft2<<<1024, 256, 0, stream>>>(x, xr, stats, tw);
  k_uvec<<<64, 256, 0, stream>>>(stats, gn_w, gn_b, qkv_w, qkv_b, uk, uv);
  k_gntrans<<<dim3(32, 4, 8), 256, 0, stream>>>(xr, stats, gn_w, gn_b, xt);
  k_gemm_qkv<<<dim3(136, 8), 256, 0, stream>>>(qkv_w, xt, qkv_b, uk, dq,
                                               Qt, Kt, Vt);
  k_attn_mfma<<<dim3(16, 3, 32), 256, 0, stream>>>(Qt, Kt, Vt, dq, uv,
                                                   opart, lpart);
  k_gemm_proj<<<dim3(16, 4, 8), 256, 0, stream>>>(proj_w, opart, lpart,
                                                  proj_b, spec);
  k_ifft2<<<1024, 256, 0, stream>>>(spec, out, tw);
}

// Round 17
// 181.588 us; speedup vs baseline: 1.1041x; 1.1041x over previous
//
#include <hip/hip_runtime.h>
#include <hip/hip_bf16.h>

#define PI_F 3.14159265358979323846f
#define C1_EXP 0.18033688f   // log2(e)/8
#define C2_EXP 23.083120f    // 16*log2(e)

typedef __bf16 bf16x8 __attribute__((ext_vector_type(8)));
typedef float f32x4 __attribute__((ext_vector_type(4)));
typedef unsigned int uint32x4 __attribute__((ext_vector_type(4)));

__device__ __forceinline__ bf16x8 neg8(bf16x8 v) {
  union { bf16x8 b; uint32x4 u; } x;
  x.b = v;
  x.u ^= (uint32x4){0x80008000u, 0x80008000u, 0x80008000u, 0x80008000u};
  return x.b;
}

// 3-term split-accumulate: P*Q with P=Ph+Pl, Q=Qh+Ql (drop Pl*Ql ~2^-18)
#define MFMA3(acc, Ph, Pl, Qh, Ql)                                        \
  acc = __builtin_amdgcn_mfma_f32_16x16x32_bf16(Ph, Qh, acc, 0, 0, 0);    \
  acc = __builtin_amdgcn_mfma_f32_16x16x32_bf16(Ph, Ql, acc, 0, 0, 0);    \
  acc = __builtin_amdgcn_mfma_f32_16x16x32_bf16(Pl, Qh, acc, 0, 0, 0);

// Closed-form base-slot -> original column mapping.
__device__ __forceinline__ int slot2n(int slot) {
  const int pi = slot >> 1, im = slot & 1;
  int k1, k2;
  if (pi < 480)      { k1 = 1 + (pi >> 5); k2 = pi & 31; }
  else if (pi < 495) { k1 = 0;  k2 = pi - 479; }
  else if (pi < 510) { k1 = 16; k2 = pi - 494; }
  else if (pi < 514) { k1 = ((pi - 510) >> 1) * 16; k2 = ((pi - 510) & 1) * 16; }
  else               { k1 = 0; k2 = 0; }
  return 2 * (k1 * 32 + k2) + im;
}

// ---------------------------------------------------------------------------
// Kernel 0: twiddle tables, hi/lo split bf16.
// ---------------------------------------------------------------------------
__global__ __launch_bounds__(256) void k_twid(__bf16* __restrict__ tw) {
  for (int e = threadIdx.x; e < 1024; e += 256) {
    const int j = e >> 5, k = e & 31;
    const int t = (j * k) & 31;
    float sv, cv;
    sincosf(2.0f * PI_F * (float)t / 32.0f, &sv, &cv);
    const __bf16 ch = (__bf16)cv;
    const __bf16 sh = (__bf16)sv;
    tw[e] = ch;
    tw[1024 + e] = (__bf16)(cv - (float)ch);
    tw[2048 + e] = sh;
    tw[3072 + e] = (__bf16)(sv - (float)sh);
  }
}

// ---------------------------------------------------------------------------
// Kernel 1: forward FFT2 via split-bf16 MFMA. One slice per wave (r14
// measured-best barrier-free form; the r15/r16 2-wave split regressed).
// X global loads issued BEFORE table staging to overlap HBM latency.
// ---------------------------------------------------------------------------
__global__ __launch_bounds__(256) void k_fft2(const float* __restrict__ x,
                                              float* __restrict__ xr,
                                              float* __restrict__ stats_raw,
                                              const __bf16* __restrict__ tw) {
  __shared__ __align__(16) char smem[51200];
  const int tid = threadIdx.x, lane = tid & 63, wv = tid >> 6;
  const int quad = lane >> 4, q16 = lane & 15;
  const int slice = blockIdx.x * 4 + wv;
  char* const wr_ = smem + 10240 + wv * 10240;

  // early X global loads (wave-private region; overlap with table staging)
  const float* xs = x + (size_t)slice * 1024;
  float4 xv[4];
#pragma unroll
  for (int u = 0; u < 4; ++u) xv[u] = ((const float4*)xs)[u * 64 + lane];

  for (int i = tid; i < 512; i += 256) {
    const int t = i >> 7, r = (i >> 2) & 31, c8 = (i & 3) * 8;
    *(uint4*)(smem + t * 2560 + r * 80 + c8 * 2) =
        *(const uint4*)(tw + t * 1024 + r * 32 + c8);
  }

  // X split + stage (same-wave ds ordering)
#pragma unroll
  for (int u = 0; u < 4; ++u) {
    const int f = u * 64 + lane;
    const float4 v = xv[u];
    const int row = f >> 3, c4 = (f & 7) * 4;
    union { unsigned long long q; __bf16 b[4]; } ph, pl;
    ph.b[0] = (__bf16)v.x; ph.b[1] = (__bf16)v.y;
    ph.b[2] = (__bf16)v.z; ph.b[3] = (__bf16)v.w;
    pl.b[0] = (__bf16)(v.x - (float)ph.b[0]);
    pl.b[1] = (__bf16)(v.y - (float)ph.b[1]);
    pl.b[2] = (__bf16)(v.z - (float)ph.b[2]);
    pl.b[3] = (__bf16)(v.w - (float)ph.b[3]);
    *(unsigned long long*)(wr_ + row * 80 + c4 * 2) = ph.q;
    *(unsigned long long*)(wr_ + 2560 + row * 80 + c4 * 2) = pl.q;
  }
  __syncthreads();  // tables visible to all waves; X same-wave ordered

  bf16x8 cch[2], ccl[2], ssh[2], ssl[2], xh[2], xl[2];
#pragma unroll
  for (int t2 = 0; t2 < 2; ++t2) {
    const int row = t2 * 16 + q16;
    cch[t2] = *(const bf16x8*)(smem + row * 80 + quad * 16);
    ccl[t2] = *(const bf16x8*)(smem + 2560 + row * 80 + quad * 16);
    ssh[t2] = *(const bf16x8*)(smem + 5120 + row * 80 + quad * 16);
    ssl[t2] = *(const bf16x8*)(smem + 7680 + row * 80 + quad * 16);
    xh[t2] = *(const bf16x8*)(wr_ + row * 80 + quad * 16);
    xl[t2] = *(const bf16x8*)(wr_ + 2560 + row * 80 + quad * 16);
  }

  // pass 1: Yre = X@Cc, Yim = -(X@Ss)
  f32x4 yre[2][2] = {}, yim[2][2] = {};
#pragma unroll
  for (int mt = 0; mt < 2; ++mt)
#pragma unroll
    for (int nt = 0; nt < 2; ++nt) {
      MFMA3(yre[mt][nt], xh[mt], xl[mt], cch[nt], ccl[nt]);
      MFMA3(yim[mt][nt], xh[mt], xl[mt], ssh[nt], ssl[nt]);
    }

  // write Yt transposed + split (wave-private; same-wave ordering)
#pragma unroll
  for (int mt = 0; mt < 2; ++mt)
#pragma unroll
    for (int nt = 0; nt < 2; ++nt) {
      char* base = wr_ + (nt * 16 + q16) * 80 + (mt * 16 + quad * 4) * 2;
      union { unsigned long long q; __bf16 b[4]; } h, l;
#pragma unroll
      for (int r = 0; r < 4; ++r) {
        const float v = yre[mt][nt][r];
        h.b[r] = (__bf16)v; l.b[r] = (__bf16)(v - (float)h.b[r]);
      }
      *(unsigned long long*)(base) = h.q;
      *(unsigned long long*)(base + 2560) = l.q;
#pragma unroll
      for (int r = 0; r < 4; ++r) {
        const float v = -yim[mt][nt][r];
        h.b[r] = (__bf16)v; l.b[r] = (__bf16)(v - (float)h.b[r]);
      }
      *(unsigned long long*)(base + 5120) = h.q;
      *(unsigned long long*)(base + 7680) = l.q;
    }
  asm volatile("" ::: "memory");

  bf16x8 yreh[2], yrel[2], yimh[2], yiml[2];
#pragma unroll
  for (int nt = 0; nt < 2; ++nt) {
    const int row = nt * 16 + q16;
    yreh[nt] = *(const bf16x8*)(wr_ + row * 80 + quad * 16);
    yrel[nt] = *(const bf16x8*)(wr_ + 2560 + row * 80 + quad * 16);
    yimh[nt] = *(const bf16x8*)(wr_ + 5120 + row * 80 + quad * 16);
    yiml[nt] = *(const bf16x8*)(wr_ + 7680 + row * 80 + quad * 16);
  }

  // pass 2: Zre = Cc@Yre + Ss@Yim ; Zim = Cc@Yim - Ss@Yre
  f32x4 zre[2][2] = {}, zim[2][2] = {};
  bf16x8 ssnh[2], ssnl[2];
  ssnh[0] = neg8(ssh[0]); ssnh[1] = neg8(ssh[1]);
  ssnl[0] = neg8(ssl[0]); ssnl[1] = neg8(ssl[1]);
#pragma unroll
  for (int mt = 0; mt < 2; ++mt)
#pragma unroll
    for (int nt = 0; nt < 2; ++nt) {
      MFMA3(zre[mt][nt], cch[mt], ccl[mt], yreh[nt], yrel[nt]);
      MFMA3(zre[mt][nt], ssh[mt], ssl[mt], yimh[nt], yiml[nt]);
      MFMA3(zim[mt][nt], cch[mt], ccl[mt], yimh[nt], yiml[nt]);
      MFMA3(zim[mt][nt], ssnh[mt], ssnl[mt], yreh[nt], yrel[nt]);
    }

  // stats + store
  float* op = xr + (size_t)slice * 2048;
  float s1 = 0.f, s2 = 0.f;
#pragma unroll
  for (int mt = 0; mt < 2; ++mt)
#pragma unroll
    for (int nt = 0; nt < 2; ++nt)
#pragma unroll
      for (int r = 0; r < 4; ++r) {
        const int k1 = mt * 16 + quad * 4 + r;
        const int k2 = nt * 16 + q16;
        const float a = zre[mt][nt][r], bimg = zim[mt][nt][r];
        s1 += a + bimg;
        s2 += a * a + bimg * bimg;
        float2 st; st.x = a; st.y = bimg;
        *(float2*)(op + 2 * (k1 * 32 + k2)) = st;
      }
#pragma unroll
  for (int off = 1; off <= 32; off <<= 1) {
    s1 += __shfl_xor(s1, off);
    s2 += __shfl_xor(s2, off);
  }
  if (lane == 0) {
    const int bg = (slice >> 8) * 32 + ((slice & 255) >> 3);
    atomicAdd(&stats_raw[bg * 2], s1);
    atomicAdd(&stats_raw[bg * 2 + 1], s2);
  }
}

// ---------------------------------------------------------------------------
// Kernel 2: mirror-correction vectors (coalesced); unchanged.
// ---------------------------------------------------------------------------
__global__ __launch_bounds__(256) void k_uvec(const float* __restrict__ stats_raw,
                                              const float* __restrict__ gn_w,
                                              const float* __restrict__ gn_b,
                                              const float* __restrict__ qkv_w,
                                              const float* __restrict__ qkv_b,
                                              float* __restrict__ uk,
                                              float* __restrict__ uv) {
  const int blk = blockIdx.x;
  const int tid = threadIdx.x;
  const int b = blk >> 3, h = (blk >> 1) & 3, role = blk & 1;
  __shared__ float Bsh[256];
  {
    const int g = tid >> 3;
    const float S = stats_raw[(b * 32 + g) * 2];
    const float S2 = stats_raw[(b * 32 + g) * 2 + 1];
    const float mean = S * (1.0f / 16384.0f);
    const float var = S2 * (1.0f / 16384.0f) - mean * mean;
    const float rstd = rsqrtf(var + 1e-5f);
    Bsh[tid] = gn_b[tid] - mean * rstd * gn_w[tid];
  }
  __syncthreads();
  const int cp = tid >> 2, seg = tid & 3;
  const int row = h * 192 + 64 + role * 64 + cp;
  const float* wr_ = qkv_w + (size_t)row * 256 + seg * 64;
  const float* bs = Bsh + seg * 64;
  float s = 0.f;
#pragma unroll
  for (int i = 0; i < 16; ++i) {
    const float4 w4 = *(const float4*)(wr_ + i * 4);
    const float4 b4 = *(const float4*)(bs + i * 4);
    s += w4.x * b4.x + w4.y * b4.y + w4.z * b4.z + w4.w * b4.w;
  }
  s += __shfl_xor(s, 1);
  s += __shfl_xor(s, 2);
  if (seg == 0) {
    float* dst = (role == 0) ? uk : uv;
    dst[(size_t)(b * 4 + h) * 64 + cp] = s + qkv_b[row];
  }
}

// ---------------------------------------------------------------------------
// Kernel 3: GroupNorm apply + transpose to bf16 X^T [b][n][c]; unchanged.
// ---------------------------------------------------------------------------
__global__ __launch_bounds__(256) void k_gntrans(const float* __restrict__ xr,
                                                 const float* __restrict__ stats_raw,
                                                 const float* __restrict__ w,
                                                 const float* __restrict__ bias,
                                                 __bf16* __restrict__ xt) {
  const int n0 = blockIdx.x * 64;
  const int c0 = blockIdx.y * 64;
  const int b = blockIdx.z;
  __shared__ __bf16 Lt[64][72];
  const int tid = threadIdx.x;
  for (int i = tid; i < 1024; i += 256) {
    const int cl = i >> 4, c = c0 + cl, nl = (i & 15) * 4;
    const float S = stats_raw[(b * 32 + (c >> 3)) * 2];
    const float S2 = stats_raw[(b * 32 + (c >> 3)) * 2 + 1];
    const float mean = S * (1.0f / 16384.0f);
    const float var = S2 * (1.0f / 16384.0f) - mean * mean;
    const float rstd = rsqrtf(var + 1e-5f);
    const float sc = rstd * w[c];
    const float sh = bias[c] - mean * sc;
    const float4 v = *(const float4*)(xr + ((size_t)b * 256 + c) * 2048 + n0 + nl);
    Lt[nl][cl] = (__bf16)(v.x * sc + sh);
    Lt[nl + 1][cl] = (__bf16)(v.y * sc + sh);
    Lt[nl + 2][cl] = (__bf16)(v.z * sc + sh);
    Lt[nl + 3][cl] = (__bf16)(v.w * sc + sh);
  }
  __syncthreads();
  __bf16* dst = xt + (size_t)b * 524288 + (size_t)n0 * 256 + c0;
  for (int i = tid; i < 512; i += 256) {
    const int nl = i >> 3, cch = (i & 7) * 8;
    *(uint4*)(dst + (size_t)nl * 256 + cch) = *(const uint4*)&Lt[nl][cch];
  }
}

// ---------------------------------------------------------------------------
// Kernel 4: QKV GEMM (bf16 MFMA), double-buffered LDS; unchanged.
// ---------------------------------------------------------------------------
__global__ __launch_bounds__(256) void k_gemm_qkv(const float* __restrict__ W,
                                                  const __bf16* __restrict__ X,
                                                  const float* __restrict__ bias,
                                                  const float* __restrict__ uk,
                                                  float* __restrict__ dq,
                                                  __bf16* __restrict__ Qt,
                                                  __bf16* __restrict__ Kt,
                                                  __bf16* __restrict__ Vt) {
  const int tx = blockIdx.x;
  const int b = blockIdx.y;
  int role, hd, nt;
  if (tx < 64) { role = 0; hd = tx >> 4; nt = tx & 15; }
  else if (tx < 100) { role = 1; const int i = tx - 64; hd = i / 9; nt = i - hd * 9; }
  else { role = 2; const int i = tx - 100; hd = i / 9; nt = i - hd * 9; }
  const int n0 = nt * 128;
  const int bo = hd * 192 + role * 64;
  const __bf16* Xb = X + (size_t)b * 524288;

  __shared__ __align__(16) char smem[30720];
  __bf16 (*Ot)[72] = (__bf16(*)[72])smem;
  __bf16 (*Ot2)[136] = (__bf16(*)[136])smem;

  const int tid = threadIdx.x, lane = tid & 63, wv = tid >> 6;
  const int quad = lane >> 4, q16 = lane & 15, wn = wv * 32;

  const int rowA = tid >> 2, chA = (tid & 3) * 8;
  const int browB0 = tid >> 2, bchB = (tid & 3) * 8;
  const float* wA = W + (size_t)(bo + rowA) * 256 + chA;

  const int s0r = n0 + browB0, s1r = n0 + browB0 + 64;
  const int pn0 = (role == 0) ? s0r : slot2n(s0r);
  const int pn1 = (role == 0) ? s1r : slot2n(s1r);

  float4 aP0 = *(const float4*)(wA);
  float4 aP1 = *(const float4*)(wA + 4);
  uint4 bP0 = *(const uint4*)(Xb + (size_t)pn0 * 256 + bchB);
  uint4 bP1 = *(const uint4*)(Xb + (size_t)pn1 * 256 + bchB);

  f32x4 acc[4][2] = {};
  int bsel = 0;
  for (int k0 = 0; k0 < 256; k0 += 32) {
    char* const Ab = smem + bsel;
    char* const Bb = smem + bsel + 5120;
    {
      union { uint4 u; __bf16 h[8]; } pa;
      pa.h[0] = (__bf16)aP0.x; pa.h[1] = (__bf16)aP0.y;
      pa.h[2] = (__bf16)aP0.z; pa.h[3] = (__bf16)aP0.w;
      pa.h[4] = (__bf16)aP1.x; pa.h[5] = (__bf16)aP1.y;
      pa.h[6] = (__bf16)aP1.z; pa.h[7] = (__bf16)aP1.w;
      *(uint4*)(Ab + rowA * 80 + chA * 2) = pa.u;
      *(uint4*)(Bb + browB0 * 80 + bchB * 2) = bP0;
      *(uint4*)(Bb + (browB0 + 64) * 80 + bchB * 2) = bP1;
    }
    __syncthreads();
    if (k0 + 32 < 256) {
      const int kn = k0 + 32;
      aP0 = *(const float4*)(wA + kn);
      aP1 = *(const float4*)(wA + kn + 4);
      bP0 = *(const uint4*)(Xb + (size_t)pn0 * 256 + kn + bchB);
      bP1 = *(const uint4*)(Xb + (size_t)pn1 * 256 + kn + bchB);
    }
    bf16x8 af[4], bfr[2];
#pragma unroll
    for (int mt = 0; mt < 4; ++mt)
      af[mt] = *(const bf16x8*)(Ab + (mt * 16 + q16) * 80 + quad * 16);
#pragma unroll
    for (int jn = 0; jn < 2; ++jn)
      bfr[jn] = *(const bf16x8*)(Bb + (wn + jn * 16 + q16) * 80 + quad * 16);
#pragma unroll
    for (int mt = 0; mt < 4; ++mt)
#pragma unroll
      for (int jn = 0; jn < 2; ++jn)
        acc[mt][jn] = __builtin_amdgcn_mfma_f32_16x16x32_bf16(af[mt], bfr[jn], acc[mt][jn], 0, 0, 0);
    bsel ^= 15360;
  }
  __syncthreads();

  const int bh = b * 4 + hd;
  if (role == 2) {
#pragma unroll
    for (int mt = 0; mt < 4; ++mt)
#pragma unroll
      for (int r = 0; r < 4; ++r) {
        const int c = mt * 16 + quad * 4 + r;
        const float bv = bias[bo + c];
#pragma unroll
        for (int jn = 0; jn < 2; ++jn)
          Ot2[c][wn + jn * 16 + q16] = (__bf16)(acc[mt][jn][r] + bv);
      }
    __syncthreads();
    __bf16* dst = Vt + (size_t)bh * 73728;  // [c][1152]
    for (int i = tid; i < 1024; i += 256) {
      const int c = i >> 4, sg = (i & 15) * 8;
      *(uint4*)(dst + (size_t)c * 1152 + n0 + sg) = *(const uint4*)&Ot2[c][sg];
    }
  } else {
    __bf16* dst = (role == 0 ? Qt + (size_t)bh * 131072
                             : Kt + (size_t)bh * 73728);  // [n][64]
#pragma unroll
    for (int mt = 0; mt < 4; ++mt)
#pragma unroll
      for (int r = 0; r < 4; ++r) {
        const int c = mt * 16 + quad * 4 + r;
        const float bv = bias[bo + c];
#pragma unroll
        for (int jn = 0; jn < 2; ++jn)
          Ot[wn + jn * 16 + q16][c] = (__bf16)(acc[mt][jn][r] + bv);
      }
    __syncthreads();
    for (int i = tid; i < 1024; i += 256) {
      const int nl = i >> 3, cch = (i & 7) * 8;
      *(uint4*)(dst + (size_t)(n0 + nl) * 64 + cch) = *(const uint4*)&Ot[nl][cch];
    }
    if (role == 0 && tid < 128) {
      const float* ukp = uk + (size_t)bh * 64;
      float dv = 0.f;
#pragma unroll
      for (int g8 = 0; g8 < 8; ++g8) {
        const bf16x8 qv = *(const bf16x8*)&Ot[tid][g8 * 8];
#pragma unroll
        for (int k = 0; k < 8; ++k) dv += (float)qv[k] * ukp[g8 * 8 + k];
      }
      dq[(size_t)bh * 2048 + n0 + tid] = dv * (2.0f * C1_EXP);
    }
  }
}

// ---------------------------------------------------------------------------
// Kernel 5: MFMA flash attention; unchanged (weight-folded exp biases).
// ---------------------------------------------------------------------------
__global__ __launch_bounds__(256) void k_attn_mfma(const __bf16* __restrict__ Qt,
                                                   const __bf16* __restrict__ Kt,
                                                   const __bf16* __restrict__ Vt,
                                                   const float* __restrict__ dq,
                                                   const float* __restrict__ uv,
                                                   __bf16* __restrict__ opart,
                                                   float* __restrict__ lpart) {
  const int t0 = blockIdx.x * 128;
  const int part = blockIdx.y;  // 0..2
  const int bh = blockIdx.z;
  const __bf16* kt = Kt + (size_t)bh * 73728;
  const __bf16* vt = Vt + (size_t)bh * 73728;

  __shared__ __align__(16) char smem[16384];

  const int tid = threadIdx.x, lane = tid & 63, wv = tid >> 6;
  const int quad = lane >> 4, q16 = lane & 15;
  const int wband = wv * 32;

  const int rK = tid >> 3, gK = tid & 7;
  char* const kw = smem + rK * 128 + ((gK ^ (rK & 7)) * 16);
  const int cV = tid >> 2, gV = tid & 3;
  char* const vw = smem + 4096 + (cV >> 1) * 128 +
                   ((((cV & 1) * 4 + gV) ^ ((cV >> 1) & 7)) * 16);
  const __bf16* const kg = kt + (size_t)rK * 64 + gK * 8;
  const __bf16* const vg = vt + (size_t)cV * 1152 + gV * 8;

  const char* krp[2][2];
#pragma unroll
  for (int j = 0; j < 2; ++j)
#pragma unroll
    for (int kk = 0; kk < 2; ++kk)
      krp[j][kk] = smem + (j * 16 + q16) * 128 + (((kk * 4 + quad) ^ (q16 & 7)) * 16);
  const int a7 = (q16 >> 1) & 7, p1 = q16 & 1;
  const char* vrp[4];
#pragma unroll
  for (int jc = 0; jc < 4; ++jc)
    vrp[jc] = smem + 4096 + (jc * 8 + (q16 >> 1)) * 128 +
              (((p1 * 4 + quad) ^ a7) * 16);
  char* pwp[2][2];
  const char* prp[2];
#pragma unroll
  for (int b = 0; b < 2; ++b) {
    const int mrow = ((wband + b * 16) >> 1) + (q16 >> 1);
    prp[b] = smem + 8192 + mrow * 128 + (((p1 * 4 + quad) ^ a7) * 16);
#pragma unroll
    for (int j = 0; j < 2; ++j)
      pwp[b][j] = smem + 8192 + mrow * 128 +
                  (((p1 * 4 + j * 2 + (quad >> 1)) ^ a7) * 16) + (quad & 1) * 8;
  }

  const __bf16* qbase = Qt + (size_t)bh * 131072;
  bf16x8 bq[2][2];
  float Dm[2];
  float4 uv4[4];
#pragma unroll
  for (int b = 0; b < 2; ++b) {
    const int t = t0 + wband + b * 16 + q16;
    const __bf16* qp = qbase + (size_t)t * 64 + quad * 8;
    bq[b][0] = *(const bf16x8*)qp;
    bq[b][1] = *(const bf16x8*)(qp + 32);
    Dm[b] = dq[(size_t)bh * 2048 + t] - C2_EXP;
  }
  {
    const float* uvp = uv + (size_t)bh * 64;
#pragma unroll
    for (int jc = 0; jc < 4; ++jc)
      uv4[jc] = *(const float4*)(uvp + jc * 16 + quad * 4);
  }

  f32x4 oacc[2][4] = {};
  float lsum[2] = {0.f, 0.f};
  float spsum[2] = {0.f, 0.f};

  const int sbase = part * 352, send = sbase + 352;
  uint4 kA = *(const uint4*)(kg + (size_t)sbase * 64);
  uint4 vA = *(const uint4*)(vg + sbase);

  for (int s0 = sbase; s0 < send; s0 += 32) {
    *(uint4*)kw = kA;
    *(uint4*)vw = vA;
    __syncthreads();
    if (s0 + 32 < send) {
      kA = *(const uint4*)(kg + (size_t)(s0 + 32) * 64);
      vA = *(const uint4*)(vg + s0 + 32);
    }

    f32x4 sacc[2][2] = {};
#pragma unroll
    for (int j = 0; j < 2; ++j)
#pragma unroll
      for (int kk = 0; kk < 2; ++kk) {
        const bf16x8 ak = *(const bf16x8*)krp[j][kk];
        sacc[0][j] = __builtin_amdgcn_mfma_f32_16x16x32_bf16(ak, bq[0][kk], sacc[0][j], 0, 0, 0);
        sacc[1][j] = __builtin_amdgcn_mfma_f32_16x16x32_bf16(ak, bq[1][kk], sacc[1][j], 0, 0, 0);
      }

#pragma unroll
    for (int b = 0; b < 2; ++b) {
      float lacc = 0.f, spacc = 0.f;
#pragma unroll
      for (int j = 0; j < 2; ++j) {
        const int sg = s0 + j * 16 + quad * 4;
        const float B0 = (sg < 1020) ? (1.0f - C2_EXP)
                                     : ((sg < 1028) ? -C2_EXP : -1e30f);
        const float B2 = (sg + 2 < 1020) ? (1.0f - C2_EXP)
                                         : ((sg + 2 < 1028) ? -C2_EXP : -1e30f);
        const float Bv1 = (sg + 1 < 1028) ? -C2_EXP : -1e30f;
        const float Bv3 = (sg + 3 < 1028) ? -C2_EXP : -1e30f;
        const float Bm1 = (sg + 1 < 1020) ? Dm[b] : -1e30f;
        const float Bm3 = (sg + 3 < 1020) ? Dm[b] : -1e30f;
        const float P0  = exp2f(fmaf(sacc[b][j][0], C1_EXP, B0));
        const float Pv1 = exp2f(fmaf(sacc[b][j][1], C1_EXP, Bv1));
        const float P2  = exp2f(fmaf(sacc[b][j][2], C1_EXP, B2));
        const float Pv3 = exp2f(fmaf(sacc[b][j][3], C1_EXP, Bv3));
        const float pm1 = exp2f(fmaf(sacc[b][j][1], -C1_EXP, Bm1));
        const float pm3 = exp2f(fmaf(sacc[b][j][3], -C1_EXP, Bm3));
        lacc += (P0 + P2) + (Pv1 + Pv3) + (pm1 + pm3);
        spacc += pm1 + pm3;
        union { uint2 u; __bf16 h[4]; } pk;
        pk.h[0] = (__bf16)P0;
        pk.h[1] = (__bf16)(Pv1 - pm1);
        pk.h[2] = (__bf16)P2;
        pk.h[3] = (__bf16)(Pv3 - pm3);
        *(uint2*)pwp[b][j] = pk.u;
      }
      lsum[b] += lacc;
      spsum[b] += spacc;
    }
    asm volatile("" ::: "memory");

    bf16x8 bp[2];
    bp[0] = *(const bf16x8*)prp[0];
    bp[1] = *(const bf16x8*)prp[1];
#pragma unroll
    for (int jc = 0; jc < 4; ++jc) {
      const bf16x8 av = *(const bf16x8*)vrp[jc];
      oacc[0][jc] = __builtin_amdgcn_mfma_f32_16x16x32_bf16(av, bp[0], oacc[0][jc], 0, 0, 0);
      oacc[1][jc] = __builtin_amdgcn_mfma_f32_16x16x32_bf16(av, bp[1], oacc[1][jc], 0, 0, 0);
    }
    __syncthreads();
  }

#pragma unroll
  for (int b = 0; b < 2; ++b) {
    float l = lsum[b], sp = spsum[b];
    l += __shfl_xor(l, 16);
    l += __shfl_xor(l, 32);
    sp += __shfl_xor(sp, 16);
    sp += __shfl_xor(sp, 32);
    const float sp2 = 2.0f * sp;
    const int t = t0 + wband + b * 16 + q16;
    const size_t row = (size_t)(bh * 3 + part) * 2048 + t;
    if (quad == 0) lpart[row] = l;
    __bf16* opp = opart + row * 64;
#pragma unroll
    for (int jc = 0; jc < 4; ++jc) {
      union { uint2 u; __bf16 h[4]; } pk;
      pk.h[0] = (__bf16)(oacc[b][jc][0] + sp2 * uv4[jc].x);
      pk.h[1] = (__bf16)(oacc[b][jc][1] + sp2 * uv4[jc].y);
      pk.h[2] = (__bf16)(oacc[b][jc][2] + sp2 * uv4[jc].z);
      pk.h[3] = (__bf16)(oacc[b][jc][3] + sp2 * uv4[jc].w);
      *(uint2*)(opp + jc * 16 + quad * 4) = pk.u;
    }
  }
}

// ---------------------------------------------------------------------------
// Kernel 6: proj GEMM (bf16 MFMA), double-buffered, fused 3-way combine;
// unchanged.
// ---------------------------------------------------------------------------
__global__ __launch_bounds__(256) void k_gemm_proj(const float* __restrict__ W,
                                                   const __bf16* __restrict__ opart,
                                                   const float* __restrict__ lpart,
                                                   const float* __restrict__ bias,
                                                   float* __restrict__ C) {
  const int n0 = blockIdx.x * 128;
  const int bo = blockIdx.y * 64;
  const int b = blockIdx.z;
  float* Cb = C + (size_t)b * 524288;

  __shared__ __align__(16) char smem[30720];

  const int tid = threadIdx.x, lane = tid & 63, wv = tid >> 6;
  const int quad = lane >> 4, q16 = lane & 15, wn = wv * 32;

  const int rowA = tid >> 2, chA = (tid & 3) * 8;
  const int browB0 = tid >> 2, bchB = (tid & 3) * 8;
  const float* wA = W + (size_t)(bo + rowA) * 256 + chA;

  float linv[2][4];
#pragma unroll
  for (int g = 0; g < 2; ++g) {
    const int t = n0 + browB0 + g * 64;
#pragma unroll
    for (int hd = 0; hd < 4; ++hd) {
      const size_t rr = (size_t)((b * 4 + hd) * 3) * 2048 + t;
      linv[g][hd] = 1.0f / (lpart[rr] + lpart[rr + 2048] + lpart[rr + 4096]);
    }
  }

  float4 aP0 = *(const float4*)(wA);
  float4 aP1 = *(const float4*)(wA + 4);
  bf16x8 oP[2][3];
#pragma unroll
  for (int g = 0; g < 2; ++g) {
    const int t = n0 + browB0 + g * 64;
    const size_t rr = (size_t)(b * 4 * 3) * 2048 + t;
#pragma unroll
    for (int p = 0; p < 3; ++p)
      oP[g][p] = *(const bf16x8*)(opart + (rr + p * 2048) * 64 + bchB);
  }

  f32x4 acc[4][2] = {};
  int bsel = 0;
  for (int k0 = 0; k0 < 256; k0 += 32) {
    char* const Ab = smem + bsel;
    char* const Bb = smem + bsel + 5120;
    {
      union { uint4 u; __bf16 h[8]; } pa;
      pa.h[0] = (__bf16)aP0.x; pa.h[1] = (__bf16)aP0.y;
      pa.h[2] = (__bf16)aP0.z; pa.h[3] = (__bf16)aP0.w;
      pa.h[4] = (__bf16)aP1.x; pa.h[5] = (__bf16)aP1.y;
      pa.h[6] = (__bf16)aP1.z; pa.h[7] = (__bf16)aP1.w;
      *(uint4*)(Ab + rowA * 80 + chA * 2) = pa.u;
      const int hd = (k0 + bchB) >> 6;
#pragma unroll
      for (int g = 0; g < 2; ++g) {
        const float inv = linv[g][hd];
        bf16x8 res;
#pragma unroll
        for (int k = 0; k < 8; ++k)
          res[k] = (__bf16)((((float)oP[g][0][k] + (float)oP[g][1][k]) +
                             (float)oP[g][2][k]) * inv);
        *(bf16x8*)(Bb + (browB0 + g * 64) * 80 + bchB * 2) = res;
      }
    }
    __syncthreads();
    if (k0 + 32 < 256) {
      const int kn = k0 + 32;
      aP0 = *(const float4*)(wA + kn);
      aP1 = *(const float4*)(wA + kn + 4);
      const int c = kn + bchB;
      const int hd = c >> 6, cu = c & 63;
#pragma unroll
      for (int g = 0; g < 2; ++g) {
        const int t = n0 + browB0 + g * 64;
        const size_t rr = (size_t)((b * 4 + hd) * 3) * 2048 + t;
#pragma unroll
        for (int p = 0; p < 3; ++p)
          oP[g][p] = *(const bf16x8*)(opart + (rr + p * 2048) * 64 + cu);
      }
    }
    bf16x8 af[4], bfr[2];
#pragma unroll
    for (int mt = 0; mt < 4; ++mt)
      af[mt] = *(const bf16x8*)(Ab + (mt * 16 + q16) * 80 + quad * 16);
#pragma unroll
    for (int jn = 0; jn < 2; ++jn)
      bfr[jn] = *(const bf16x8*)(Bb + (wn + jn * 16 + q16) * 80 + quad * 16);
#pragma unroll
    for (int mt = 0; mt < 4; ++mt)
#pragma unroll
      for (int jn = 0; jn < 2; ++jn)
        acc[mt][jn] = __builtin_amdgcn_mfma_f32_16x16x32_bf16(af[mt], bfr[jn], acc[mt][jn], 0, 0, 0);
    bsel ^= 15360;
  }

#pragma unroll
  for (int mt = 0; mt < 4; ++mt)
#pragma unroll
    for (int r = 0; r < 4; ++r) {
      const int o = bo + mt * 16 + quad * 4 + r;
      const float bv = bias[o];
#pragma unroll
      for (int jn = 0; jn < 2; ++jn)
        Cb[(size_t)o * 2048 + n0 + wn + jn * 16 + q16] = acc[mt][jn][r] + bv;
    }
}

// ---------------------------------------------------------------------------
// Kernel 7: inverse FFT2 via split-bf16 MFMA. One slice per wave (r14 form),
// spec global loads issued before table staging.
// ---------------------------------------------------------------------------
__global__ __launch_bounds__(256) void k_ifft2(const float* __restrict__ spec,
                                               float* __restrict__ out,
                                               const __bf16* __restrict__ tw) {
  __shared__ __align__(16) char smem[51200];
  const int tid = threadIdx.x, lane = tid & 63, wv = tid >> 6;
  const int quad = lane >> 4, q16 = lane & 15;
  const int slice = blockIdx.x * 4 + wv;
  char* const wr_ = smem + 10240 + wv * 10240;

  // early spec global loads
  const float* sp = spec + (size_t)slice * 2048;
  float4 sv8[8];
#pragma unroll
  for (int u = 0; u < 8; ++u) sv8[u] = ((const float4*)sp)[u * 64 + lane];

  for (int i = tid; i < 512; i += 256) {
    const int t = i >> 7, r = (i >> 2) & 31, c8 = (i & 3) * 8;
    *(uint4*)(smem + t * 2560 + r * 80 + c8 * 2) =
        *(const uint4*)(tw + t * 1024 + r * 32 + c8);
  }

#pragma unroll
  for (int u = 0; u < 8; ++u) {
    const int f = u * 64 + lane;  // 0..511 float4 (2 complex each)
    const float4 v = sv8[u];
    const int k1 = f >> 4, k2 = (f & 15) * 2;
    char* base = wr_ + k1 * 80 + k2 * 2;
    union { unsigned int w; __bf16 b[2]; } p;
    const __bf16 rh0 = (__bf16)v.x, rh1 = (__bf16)v.z;
    const __bf16 ih0 = (__bf16)v.y, ih1 = (__bf16)v.w;
    p.b[0] = rh0; p.b[1] = rh1; *(unsigned int*)(base) = p.w;
    p.b[0] = (__bf16)(v.x - (float)rh0);
    p.b[1] = (__bf16)(v.z - (float)rh1); *(unsigned int*)(base + 2560) = p.w;
    p.b[0] = ih0; p.b[1] = ih1; *(unsigned int*)(base + 5120) = p.w;
    p.b[0] = (__bf16)(v.y - (float)ih0);
    p.b[1] = (__bf16)(v.w - (float)ih1); *(unsigned int*)(base + 7680) = p.w;
  }
  __syncthreads();  // tables visible; X same-wave ordered

  bf16x8 cch[2], ccl[2], ssh[2], ssl[2], ssnh[2], ssnl[2];
  bf16x8 xreh[2], xrel[2], ximh[2], ximl[2];
#pragma unroll
  for (int t2 = 0; t2 < 2; ++t2) {
    const int row = t2 * 16 + q16;
    cch[t2] = *(const bf16x8*)(smem + row * 80 + quad * 16);
    ccl[t2] = *(const bf16x8*)(smem + 2560 + row * 80 + quad * 16);
    ssh[t2] = *(const bf16x8*)(smem + 5120 + row * 80 + quad * 16);
    ssl[t2] = *(const bf16x8*)(smem + 7680 + row * 80 + quad * 16);
    xreh[t2] = *(const bf16x8*)(wr_ + row * 80 + quad * 16);
    xrel[t2] = *(const bf16x8*)(wr_ + 2560 + row * 80 + quad * 16);
    ximh[t2] = *(const bf16x8*)(wr_ + 5120 + row * 80 + quad * 16);
    ximl[t2] = *(const bf16x8*)(wr_ + 7680 + row * 80 + quad * 16);
  }
  ssnh[0] = neg8(ssh[0]); ssnh[1] = neg8(ssh[1]);
  ssnl[0] = neg8(ssl[0]); ssnl[1] = neg8(ssl[1]);

  // pass 1
  f32x4 yre[2][2] = {}, yim[2][2] = {};
#pragma unroll
  for (int mt = 0; mt < 2; ++mt)
#pragma unroll
    for (int nt = 0; nt < 2; ++nt) {
      MFMA3(yre[mt][nt], xreh[mt], xrel[mt], cch[nt], ccl[nt]);
      MFMA3(yre[mt][nt], ximh[mt], ximl[mt], ssnh[nt], ssnl[nt]);
      MFMA3(yim[mt][nt], xreh[mt], xrel[mt], ssh[nt], ssl[nt]);
      MFMA3(yim[mt][nt], ximh[mt], ximl[mt], cch[nt], ccl[nt]);
    }

  // write Yt transposed + split over the X regions (wave-private)
#pragma unroll
  for (int mt = 0; mt < 2; ++mt)
#pragma unroll
    for (int nt = 0; nt < 2; ++nt) {
      char* base = wr_ + (nt * 16 + q16) * 80 + (mt * 16 + quad * 4) * 2;
      union { unsigned long long q; __bf16 b[4]; } h, l;
#pragma unroll
      for (int r = 0; r < 4; ++r) {
        const float v = yre[mt][nt][r];
        h.b[r] = (__bf16)v; l.b[r] = (__bf16)(v - (float)h.b[r]);
      }
      *(unsigned long long*)(base) = h.q;
      *(unsigned long long*)(base + 2560) = l.q;
#pragma unroll
      for (int r = 0; r < 4; ++r) {
        const float v = yim[mt][nt][r];
        h.b[r] = (__bf16)v; l.b[r] = (__bf16)(v - (float)h.b[r]);
      }
      *(unsigned long long*)(base + 5120) = h.q;
      *(unsigned long long*)(base + 7680) = l.q;
    }
  asm volatile("" ::: "memory");

  bf16x8 yreh[2], yrel[2], yimh[2], yiml[2];
#pragma unroll
  for (int nt = 0; nt < 2; ++nt) {
    const int row = nt * 16 + q16;
    yreh[nt] = *(const bf16x8*)(wr_ + row * 80 + quad * 16);
    yrel[nt] = *(const bf16x8*)(wr_ + 2560 + row * 80 + quad * 16);
    yimh[nt] = *(const bf16x8*)(wr_ + 5120 + row * 80 + quad * 16);
    yiml[nt] = *(const bf16x8*)(wr_ + 7680 + row * 80 + quad * 16);
  }

  // pass 2
  f32x4 zre[2][2] = {}, zim[2][2] = {};
#pragma unroll
  for (int mt = 0; mt < 2; ++mt)
#pragma unroll
    for (int nt = 0; nt < 2; ++nt) {
      MFMA3(zre[mt][nt], cch[mt], ccl[mt], yreh[nt], yrel[nt]);
      MFMA3(zre[mt][nt], ssnh[mt], ssnl[mt], yimh[nt], yiml[nt]);
      MFMA3(zim[mt][nt], cch[mt], ccl[mt], yimh[nt], yiml[nt]);
      MFMA3(zim[mt][nt], ssh[mt], ssl[mt], yreh[nt], yrel[nt]);
    }

  float* op = out + (size_t)slice * 2048;
#pragma unroll
  for (int mt = 0; mt < 2; ++mt)
#pragma unroll
    for (int nt = 0; nt < 2; ++nt)
#pragma unroll
      for (int r = 0; r < 4; ++r) {
        const int n1 = mt * 16 + quad * 4 + r;
        const int n2 = nt * 16 + q16;
        float2 st;
        st.x = zre[mt][nt][r] * (1.0f / 1024.0f);
        st.y = zim[mt][nt][r] * (1.0f / 1024.0f);
        *(float2*)(op + 2 * (n1 * 32 + n2)) = st;
      }
}

// ---------------------------------------------------------------------------
extern "C" void kernel_launch(void* const* d_in, const int* in_sizes, int n_in,
                              void* d_out, int out_size, void* d_ws, size_t ws_size,
                              hipStream_t stream) {
  (void)in_sizes; (void)n_in; (void)out_size; (void)ws_size;
  const float* x      = (const float*)d_in[0];
  const float* gn_w   = (const float*)d_in[1];
  const float* gn_b   = (const float*)d_in[2];
  const float* qkv_w  = (const float*)d_in[3];
  const float* qkv_b  = (const float*)d_in[4];
  const float* proj_w = (const float*)d_in[5];
  const float* proj_b = (const float*)d_in[6];
  float* out = (float*)d_out;

  float* spec  = (float*)d_ws;
  __bf16* Qt   = (__bf16*)(spec + 4194304);   // 4194304 elems
  __bf16* Kt   = Qt + 4194304;                // 2359296 elems (32*1152*64)
  __bf16* Vt   = Kt + 2359296;                // 2359296 elems
  float* stats = (float*)(Vt + 2359296);      // 512
  float* xr    = stats + 512;                 // 4194304 floats
  __bf16* xt   = (__bf16*)(xr + 4194304);     // 4194304 bf16
  __bf16* opart = (__bf16*)xr;                // 12582912 bf16 (clobbers xr+xt)
  float*  lpart = (float*)(opart + 12582912); // 196608
  float*  dq    = lpart + 196608;             // 65536
  float*  uk    = dq + 65536;                 // 2048
  float*  uv    = uk + 2048;                  // 2048
  __bf16* tw    = (__bf16*)(uv + 2048);       // 4096 bf16 twiddle tables

  hipMemsetAsync(stats, 0, 512 * sizeof(float), stream);
  k_twid<<<1, 256, 0, stream>>>(tw);
  k_fft2<<<512, 256, 0, stream>>>(x, xr, stats, tw);
  k_uvec<<<64, 256, 0, stream>>>(stats, gn_w, gn_b, qkv_w, qkv_b, uk, uv);
  k_gntrans<<<dim3(32, 4, 8), 256, 0, stream>>>(xr, stats, gn_w, gn_b, xt);
  k_gemm_qkv<<<dim3(136, 8), 256, 0, stream>>>(qkv_w, xt, qkv_b, uk, dq,
                                               Qt, Kt, Vt);
  k_attn_mfma<<<dim3(16, 3, 32), 256, 0, stream>>>(Qt, Kt, Vt, dq, uv,
                                                   opart, lpart);
  k_gemm_proj<<<dim3(16, 4, 8), 256, 0, stream>>>(proj_w, opart, lpart,
                                                  proj_b, spec);
  k_ifft2<<<512, 256, 0, stream>>>(spec, out, tw);
}